// Round 1
// baseline (250.041 us; speedup 1.0000x reference)
//
#include <hip/hip_runtime.h>

// Problem constants (from reference)
#define NB    32
#define KJ    17
#define CIN   2048
#define HWSZ  4096     // H*W = 64*64
#define WDIM  64
#define CEMB  2112     // 64 + 2048
#define HID   128
#define NROWS (NB*KJ)  // 544

// Skeleton adjacency mask (H36M edges + diagonal), row i -> bitmask over j
__device__ __constant__ unsigned c_mask[KJ] = {
  0x00093u, // 0: {0,1,4,7}
  0x00007u, // 1: {0,1,2}
  0x0000Eu, // 2: {1,2,3}
  0x0000Cu, // 3: {2,3}
  0x00031u, // 4: {0,4,5}
  0x00070u, // 5: {4,5,6}
  0x00060u, // 6: {5,6}
  0x00181u, // 7: {0,7,8}
  0x04B80u, // 8: {7,8,9,11,14}
  0x00700u, // 9: {8,9,10}
  0x00600u, // 10:{9,10}
  0x01900u, // 11:{8,11,12}
  0x03800u, // 12:{11,12,13}
  0x03000u, // 13:{12,13}
  0x0C100u, // 14:{8,14,15}
  0x1C000u, // 15:{14,15,16}
  0x18000u  // 16:{15,16}
};

// ---------------------------------------------------------------------------
// K_A: per-(n,k) heatmap argmax + feature gather + posemb MLP -> h[544][2112]
// ---------------------------------------------------------------------------
__global__ __launch_bounds__(256) void k_gather(
    const float* __restrict__ x, const float* __restrict__ heatmap,
    const float* __restrict__ bbox, const float* __restrict__ pos_w,
    const float* __restrict__ pos_b, float* __restrict__ h_ws) {
  const int b = blockIdx.x;          // n*17 + k
  const int n = b / KJ;
  const int t = threadIdx.x;

  __shared__ float svals[256];
  __shared__ int   sidx[256];

  // argmax over 4096, first-index tie-break (jnp.argmax semantics)
  const float4* hm4 = (const float4*)(heatmap + (size_t)b * HWSZ);
  float best = -1e30f; int bidx = 0;
  #pragma unroll
  for (int k = 0; k < 4; ++k) {
    const int vi = k * 256 + t;
    const float4 v = hm4[vi];
    const int base = vi * 4;
    if (v.x > best) { best = v.x; bidx = base;     }
    if (v.y > best) { best = v.y; bidx = base + 1; }
    if (v.z > best) { best = v.z; bidx = base + 2; }
    if (v.w > best) { best = v.w; bidx = base + 3; }
  }
  svals[t] = best; sidx[t] = bidx;
  __syncthreads();
  for (int s = 128; s > 0; s >>= 1) {
    if (t < s) {
      const float v2 = svals[t + s]; const int i2 = sidx[t + s];
      if (v2 > svals[t] || (v2 == svals[t] && i2 < sidx[t])) {
        svals[t] = v2; sidx[t] = i2;
      }
    }
    __syncthreads();
  }
  const int loc = sidx[0];

  float* hrow = h_ws + (size_t)b * CEMB;

  // posemb: 6-vector @ pos_w[6][64] + pos_b
  if (t < 64) {
    const float kx = (float)(loc & (WDIM - 1));
    const float ky = (float)(loc >> 6);
    float in6[6];
    in6[0] = kx * (2.0f / 64.0f) - 1.0f;
    in6[1] = ky * (2.0f / 64.0f) - 1.0f;
    in6[2] = bbox[n * 4 + 0] * (2.0f / 1920.0f) - 1.0f;
    in6[3] = bbox[n * 4 + 1] * (2.0f / 1080.0f) - 1.0f;
    in6[4] = bbox[n * 4 + 2] * (1.0f / 1920.0f);
    in6[5] = bbox[n * 4 + 3] * (1.0f / 1080.0f);
    float acc = pos_b[t];
    #pragma unroll
    for (int c = 0; c < 6; ++c) acc = fmaf(in6[c], pos_w[c * 64 + t], acc);
    hrow[t] = acc;
  }

  // feature gather: x[n, c, loc], stride HWSZ between channels (scattered)
  const float* xn = x + (size_t)n * CIN * HWSZ + loc;
  for (int c = t; c < CIN; c += 256) {
    hrow[64 + c] = xn[(size_t)c * HWSZ];
  }
}

// ---------------------------------------------------------------------------
// K_B: input GEMM  C[544][256] = h[544][2112] @ [Wi0|Wi1], split-K=2
// grid (34, 4, 2), block 256.  part[z][544][256] partial sums in ws.
// ---------------------------------------------------------------------------
__global__ __launch_bounds__(256) void k_gemm_in(
    const float* __restrict__ h_ws, const float* __restrict__ Wi,
    float* __restrict__ part) {
  const int bm = blockIdx.x, bn = blockIdx.y, bz = blockIdx.z;
  const int t = threadIdx.x;
  const int lane = t & 63, g = t >> 6;          // wave-uniform row group
  const int j = bn * 64 + lane;                 // output col 0..255
  const int p = j >> 7, d = j & 127;
  const float* W = Wi + (size_t)p * CEMB * HID + d;
  const int row0 = bm * 16;

  __shared__ float At[16][32];
  float acc[4] = {0.f, 0.f, 0.f, 0.f};

  const int k0 = bz * 1056, k1 = k0 + 1056;     // 1056 = 2112/2, 33 tiles of 32
  for (int kk = k0; kk < k1; kk += 32) {
    __syncthreads();
    for (int idx = t; idx < 16 * 32; idx += 256) {
      const int r = idx >> 5, c = idx & 31;
      At[r][c] = h_ws[(size_t)(row0 + r) * CEMB + kk + c];
    }
    __syncthreads();
    #pragma unroll 2
    for (int c = 0; c < 32; c += 4) {
      const float w0 = W[(size_t)(kk + c + 0) * HID];
      const float w1 = W[(size_t)(kk + c + 1) * HID];
      const float w2 = W[(size_t)(kk + c + 2) * HID];
      const float w3 = W[(size_t)(kk + c + 3) * HID];
      #pragma unroll
      for (int r = 0; r < 4; ++r) {
        const float4 s = *(const float4*)&At[g * 4 + r][c];
        acc[r] = fmaf(s.x, w0, fmaf(s.y, w1, fmaf(s.z, w2, fmaf(s.w, w3, acc[r]))));
      }
    }
  }
  #pragma unroll
  for (int r = 0; r < 4; ++r) {
    part[((size_t)bz * NROWS + row0 + g * 4 + r) * 256 + j] = acc[r];
  }
}

// ---------------------------------------------------------------------------
// K_C: adjacency softmax + input mix + 4 residual blocks (8 gconvs) + output
// grid 32 (one block per sample), block 256.
// ---------------------------------------------------------------------------
__device__ __forceinline__ void layer_compute(
    const float (*S)[HID], const float* __restrict__ Wl,
    float (*O0)[HID], float (*O1)[HID], int t) {
  // thread -> (half, col j). half 0: rows 0..8, half 1: rows 9..17 (17 = pad)
  const int half = t >> 7;
  const int j = t & 127;
  const int r0 = half * 9;
  const float* W0 = Wl + j;             // W[0][c][j], stride HID over c
  const float* W1 = Wl + HID * HID + j; // W[1][c][j]
  float a0[9], a1[9];
  #pragma unroll
  for (int r = 0; r < 9; ++r) { a0[r] = 0.f; a1[r] = 0.f; }
  #pragma unroll 4
  for (int c = 0; c < HID; c += 4) {
    const float w00 = W0[(c + 0) * HID], w01 = W0[(c + 1) * HID];
    const float w02 = W0[(c + 2) * HID], w03 = W0[(c + 3) * HID];
    const float w10 = W1[(c + 0) * HID], w11 = W1[(c + 1) * HID];
    const float w12 = W1[(c + 2) * HID], w13 = W1[(c + 3) * HID];
    #pragma unroll
    for (int r = 0; r < 9; ++r) {
      const float4 s = *(const float4*)(&S[r0 + r][c]);   // wave-uniform broadcast
      a0[r] = fmaf(s.x, w00, fmaf(s.y, w01, fmaf(s.z, w02, fmaf(s.w, w03, a0[r]))));
      a1[r] = fmaf(s.x, w10, fmaf(s.y, w11, fmaf(s.z, w12, fmaf(s.w, w13, a1[r]))));
    }
  }
  #pragma unroll
  for (int r = 0; r < 9; ++r) { O0[r0 + r][j] = a0[r]; O1[r0 + r][j] = a1[r]; }
}

template <int ADD>
__device__ __forceinline__ void mix_bn(
    const float (*T0)[HID], const float (*T1)[HID], const float (*A)[KJ],
    const float* __restrict__ bias, const float* __restrict__ gamma,
    const float* __restrict__ beta, float (*dst)[HID], int t) {
  const int d = t & 127;
  const float bsv = bias[d];
  const float gsv = gamma[d] * 0.99999500003749969f;  // rsqrt(1+1e-5)
  const float btv = beta[d];
  for (int i = (t >> 7); i < KJ; i += 2) {
    float s = 0.f;
    #pragma unroll
    for (int jj = 0; jj < KJ; ++jj) s = fmaf(A[i][jj], T1[jj][d], s);
    s += A[i][i] * (T0[i][d] - T1[i][d]);   // replace diag term h1 -> h0
    const float v = fmaxf(fmaf(s + bsv, gsv, btv), 0.f);
    if (ADD) dst[i][d] += v; else dst[i][d] = v;
  }
}

__global__ __launch_bounds__(256) void k_gcn(
    const float* __restrict__ part,
    const float* __restrict__ Ei, const float* __restrict__ bi,
    const float* __restrict__ gi, const float* __restrict__ bti,
    const float* __restrict__ Wh, const float* __restrict__ bh,
    const float* __restrict__ Eh, const float* __restrict__ gh,
    const float* __restrict__ bth, const float* __restrict__ Wo,
    const float* __restrict__ bo, const float* __restrict__ Eo,
    float* __restrict__ out) {
  __shared__ float adjm[10][KJ][KJ];
  __shared__ float Hs[18][HID], Rs[18][HID], T0[18][HID], T1[18][HID];
  const int n = blockIdx.x, t = threadIdx.x;

  // 0) adjacency softmax for all 10 gconvs (Ei, Eh[0..7], Eo)
  if (t < 170) {
    const int m = t / KJ, i = t % KJ;
    const float* Es = (m == 0) ? Ei : ((m <= 8) ? Eh + (size_t)(m - 1) * KJ * KJ : Eo);
    const unsigned msk = c_mask[i];
    float mx = -1e30f;
    #pragma unroll
    for (int jj = 0; jj < KJ; ++jj)
      if (msk & (1u << jj)) mx = fmaxf(mx, Es[i * KJ + jj]);
    float ev[KJ];
    float sum = 0.f;
    #pragma unroll
    for (int jj = 0; jj < KJ; ++jj) {
      const float e = (msk & (1u << jj)) ? expf(Es[i * KJ + jj] - mx) : 0.f;
      ev[jj] = e; sum += e;
    }
    const float inv = 1.f / sum;
    #pragma unroll
    for (int jj = 0; jj < KJ; ++jj) adjm[m][i][jj] = ev[jj] * inv;
  }
  // zero pad-rows (row 17) so the padded 9th row of half=1 reads zeros
  if (t < HID) { Hs[17][t] = 0.f; Rs[17][t] = 0.f; }

  // 1) load split-K partials of input gconv h0/h1
  {
    const float* p0 = part + (size_t)(n * KJ) * 256;
    const float* p1 = part + (size_t)NROWS * 256 + (size_t)(n * KJ) * 256;
    for (int idx = t; idx < KJ * 256; idx += 256) {
      const int k = idx >> 8, jj = idx & 255;
      const float v = p0[k * 256 + jj] + p1[k * 256 + jj];
      if (jj < HID) T0[k][jj] = v; else T1[k][jj - HID] = v;
    }
  }
  __syncthreads();

  // 2) input mixing + BN + ReLU -> Hs
  mix_bn<0>(T0, T1, adjm[0], bi, gi, bti, Hs, t);
  __syncthreads();

  // 3) 4 residual blocks x 2 gconvs
  for (int l = 0; l < 4; ++l) {
    const float* WA = Wh + (size_t)(2 * l) * 2 * HID * HID;
    const float* WB = WA + 2 * HID * HID;
    layer_compute(Hs, WA, T0, T1, t);
    __syncthreads();
    mix_bn<0>(T0, T1, adjm[1 + 2 * l], bh + (2 * l) * HID, gh + (2 * l) * HID,
              bth + (2 * l) * HID, Rs, t);
    __syncthreads();
    layer_compute(Rs, WB, T0, T1, t);
    __syncthreads();
    mix_bn<1>(T0, T1, adjm[2 + 2 * l], bh + (2 * l + 1) * HID, gh + (2 * l + 1) * HID,
              bth + (2 * l + 1) * HID, Hs, t);
    __syncthreads();
  }

  // 4) output gconv (no BN/ReLU): 128 -> 3
  if (t < 102) {
    const int p = t / 51, rem = t % 51, i = rem / 3, e = rem % 3;
    const float* Wp = Wo + p * HID * 3 + e;
    float s = 0.f;
    #pragma unroll 4
    for (int c = 0; c < HID; ++c) s = fmaf(Hs[i][c], Wp[c * 3], s);
    if (p == 0) T0[i][e] = s; else T1[i][e] = s;
  }
  __syncthreads();
  if (t < 51) {
    const int i = t / 3, e = t % 3;
    const float (*A)[KJ] = adjm[9];
    float s = bo[e];
    #pragma unroll
    for (int jj = 0; jj < KJ; ++jj) s = fmaf(A[i][jj], T1[jj][e], s);
    s += A[i][i] * (T0[i][e] - T1[i][e]);
    out[(n * KJ + i) * 3 + e] = s;
  }
}

// ---------------------------------------------------------------------------
extern "C" void kernel_launch(void* const* d_in, const int* in_sizes, int n_in,
                              void* d_out, int out_size, void* d_ws, size_t ws_size,
                              hipStream_t stream) {
  const float* x       = (const float*)d_in[0];
  const float* heatmap = (const float*)d_in[1];
  const float* bbox    = (const float*)d_in[2];
  const float* pos_w   = (const float*)d_in[3];
  const float* pos_b   = (const float*)d_in[4];
  const float* Wi      = (const float*)d_in[5];
  const float* bi      = (const float*)d_in[6];
  const float* Ei      = (const float*)d_in[7];
  const float* gi      = (const float*)d_in[8];
  const float* bti     = (const float*)d_in[9];
  const float* Wh      = (const float*)d_in[10];
  const float* bh      = (const float*)d_in[11];
  const float* Eh      = (const float*)d_in[12];
  const float* gh      = (const float*)d_in[13];
  const float* bth     = (const float*)d_in[14];
  const float* Wo      = (const float*)d_in[15];
  const float* bo      = (const float*)d_in[16];
  const float* Eo      = (const float*)d_in[17];
  float* out = (float*)d_out;

  // ws layout (floats): h[544*2112] | part[2*544*256]  (~5.5 MB total)
  float* h_ws = (float*)d_ws;
  float* part = h_ws + (size_t)NROWS * CEMB;

  k_gather<<<NROWS, 256, 0, stream>>>(x, heatmap, bbox, pos_w, pos_b, h_ws);
  k_gemm_in<<<dim3(34, 4, 2), 256, 0, stream>>>(h_ws, Wi, part);
  k_gcn<<<NB, 256, 0, stream>>>(part, Ei, bi, gi, bti, Wh, bh, Eh, gh, bth,
                                Wo, bo, Eo, out);
}

// Round 2
// 236.594 us; speedup vs baseline: 1.0568x; 1.0568x over previous
//
#include <hip/hip_runtime.h>

// Problem constants (from reference)
#define NB    32
#define KJ    17
#define CIN   2048
#define HWSZ  4096     // H*W = 64*64
#define WDIM  64
#define CEMB  2112     // 64 + 2048
#define HID   128
#define NROWS (NB*KJ)  // 544
#define SPLITK 4

// Skeleton adjacency mask (H36M edges + diagonal), row i -> bitmask over j
__device__ __constant__ unsigned c_mask[KJ] = {
  0x00093u, 0x00007u, 0x0000Eu, 0x0000Cu, 0x00031u, 0x00070u, 0x00060u,
  0x00181u, 0x04B80u, 0x00700u, 0x00600u, 0x01900u, 0x03800u, 0x03000u,
  0x0C100u, 0x1C000u, 0x18000u
};

// ---------------------------------------------------------------------------
// K_loc: per-(n,k) heatmap argmax -> locs[544]; also posemb MLP -> h[:,0:64]
// ---------------------------------------------------------------------------
__global__ __launch_bounds__(256) void k_loc(
    const float* __restrict__ heatmap, const float* __restrict__ bbox,
    const float* __restrict__ pos_w, const float* __restrict__ pos_b,
    float* __restrict__ h_ws, int* __restrict__ locs) {
  const int b = blockIdx.x;          // n*17 + k
  const int n = b / KJ;
  const int t = threadIdx.x;

  __shared__ float svals[256];
  __shared__ int   sidx[256];

  // argmax over 4096, first-index tie-break (jnp.argmax semantics)
  const float4* hm4 = (const float4*)(heatmap + (size_t)b * HWSZ);
  float best = -1e30f; int bidx = 0;
  #pragma unroll
  for (int k = 0; k < 4; ++k) {
    const int vi = k * 256 + t;
    const float4 v = hm4[vi];
    const int base = vi * 4;
    if (v.x > best) { best = v.x; bidx = base;     }
    if (v.y > best) { best = v.y; bidx = base + 1; }
    if (v.z > best) { best = v.z; bidx = base + 2; }
    if (v.w > best) { best = v.w; bidx = base + 3; }
  }
  svals[t] = best; sidx[t] = bidx;
  __syncthreads();
  for (int s = 128; s > 0; s >>= 1) {
    if (t < s) {
      const float v2 = svals[t + s]; const int i2 = sidx[t + s];
      if (v2 > svals[t] || (v2 == svals[t] && i2 < sidx[t])) {
        svals[t] = v2; sidx[t] = i2;
      }
    }
    __syncthreads();
  }
  const int loc = sidx[0];
  if (t == 0) locs[b] = loc;

  // posemb: 6-vector @ pos_w[6][64] + pos_b
  if (t < 64) {
    const float kx = (float)(loc & (WDIM - 1));
    const float ky = (float)(loc >> 6);
    float in6[6];
    in6[0] = kx * (2.0f / 64.0f) - 1.0f;
    in6[1] = ky * (2.0f / 64.0f) - 1.0f;
    in6[2] = bbox[n * 4 + 0] * (2.0f / 1920.0f) - 1.0f;
    in6[3] = bbox[n * 4 + 1] * (2.0f / 1080.0f) - 1.0f;
    in6[4] = bbox[n * 4 + 2] * (1.0f / 1920.0f);
    in6[5] = bbox[n * 4 + 3] * (1.0f / 1080.0f);
    float acc = pos_b[t];
    #pragma unroll
    for (int c = 0; c < 6; ++c) acc = fmaf(in6[c], pos_w[c * 64 + t], acc);
    h_ws[(size_t)b * CEMB + t] = acc;
  }
}

// ---------------------------------------------------------------------------
// K_feat: scattered feature gather x[n, c, loc] -> h[:,64:2112]
// grid (544, 4): block = (row b, channel chunk of 512). 2 loads/thread.
// ---------------------------------------------------------------------------
__global__ __launch_bounds__(256) void k_feat(
    const float* __restrict__ x, const int* __restrict__ locs,
    float* __restrict__ h_ws) {
  const int b = blockIdx.x;
  const int n = b / KJ;
  const int t = threadIdx.x;
  const int loc = locs[b];
  const int c0 = blockIdx.y * 512 + t;
  const float* xn = x + (size_t)n * CIN * HWSZ + loc;
  float* hrow = h_ws + (size_t)b * CEMB + 64;
  const float v0 = __builtin_nontemporal_load(xn + (size_t)c0 * HWSZ);
  const float v1 = __builtin_nontemporal_load(xn + (size_t)(c0 + 256) * HWSZ);
  hrow[c0] = v0;
  hrow[c0 + 256] = v1;
}

// ---------------------------------------------------------------------------
// K_B: input GEMM  C[544][256] = h[544][2112] @ [Wi0|Wi1], split-K=4
// grid (34, 4, 4), block 256.  part[z][544][256] partial sums in ws.
// K per z = 528 = 22 tiles x 24.
// ---------------------------------------------------------------------------
__global__ __launch_bounds__(256) void k_gemm_in(
    const float* __restrict__ h_ws, const float* __restrict__ Wi,
    float* __restrict__ part) {
  const int bm = blockIdx.x, bn = blockIdx.y, bz = blockIdx.z;
  const int t = threadIdx.x;
  const int lane = t & 63, g = t >> 6;          // wave-uniform row group
  const int j = bn * 64 + lane;                 // output col 0..255
  const int p = j >> 7, d = j & 127;
  const float* W = Wi + (size_t)p * CEMB * HID + d;
  const int row0 = bm * 16;

  __shared__ float At[16][24];
  float acc[4] = {0.f, 0.f, 0.f, 0.f};

  const int k0 = bz * 528, k1 = k0 + 528;
  for (int kk = k0; kk < k1; kk += 24) {
    __syncthreads();
    for (int idx = t; idx < 16 * 24; idx += 256) {
      const int r = idx / 24, c = idx - r * 24;
      At[r][c] = h_ws[(size_t)(row0 + r) * CEMB + kk + c];
    }
    __syncthreads();
    #pragma unroll
    for (int c = 0; c < 24; c += 4) {
      const float w0 = W[(size_t)(kk + c + 0) * HID];
      const float w1 = W[(size_t)(kk + c + 1) * HID];
      const float w2 = W[(size_t)(kk + c + 2) * HID];
      const float w3 = W[(size_t)(kk + c + 3) * HID];
      #pragma unroll
      for (int r = 0; r < 4; ++r) {
        const float4 s = *(const float4*)&At[g * 4 + r][c];
        acc[r] = fmaf(s.x, w0, fmaf(s.y, w1, fmaf(s.z, w2, fmaf(s.w, w3, acc[r]))));
      }
    }
  }
  #pragma unroll
  for (int r = 0; r < 4; ++r) {
    part[((size_t)bz * NROWS + row0 + g * 4 + r) * 256 + j] = acc[r];
  }
}

// ---------------------------------------------------------------------------
// K_C: adjacency softmax + input mix + 4 residual blocks (8 gconvs) + output
// grid 32 (one block per sample), block 512.
// thread -> (quarter q = t>>7 owning 5 rows, col j = t&127)
// ---------------------------------------------------------------------------
__device__ __forceinline__ void layer_compute(
    const float (*S)[HID], const float* __restrict__ Wl,
    float (*O0)[HID], float (*O1)[HID], int t) {
  const int q = t >> 7;
  const int j = t & 127;
  const int r0 = q * 5;                 // rows r0..r0+4 (rows 17..19 are pad)
  const float* W0 = Wl + j;             // W[0][c][j], stride HID over c
  const float* W1 = Wl + HID * HID + j; // W[1][c][j]
  float a0[5], a1[5];
  #pragma unroll
  for (int r = 0; r < 5; ++r) { a0[r] = 0.f; a1[r] = 0.f; }
  #pragma unroll 4
  for (int c = 0; c < HID; c += 4) {
    const float w00 = W0[(c + 0) * HID], w01 = W0[(c + 1) * HID];
    const float w02 = W0[(c + 2) * HID], w03 = W0[(c + 3) * HID];
    const float w10 = W1[(c + 0) * HID], w11 = W1[(c + 1) * HID];
    const float w12 = W1[(c + 2) * HID], w13 = W1[(c + 3) * HID];
    #pragma unroll
    for (int r = 0; r < 5; ++r) {
      const float4 s = *(const float4*)(&S[r0 + r][c]);   // wave-uniform broadcast
      a0[r] = fmaf(s.x, w00, fmaf(s.y, w01, fmaf(s.z, w02, fmaf(s.w, w03, a0[r]))));
      a1[r] = fmaf(s.x, w10, fmaf(s.y, w11, fmaf(s.z, w12, fmaf(s.w, w13, a1[r]))));
    }
  }
  #pragma unroll
  for (int r = 0; r < 5; ++r) { O0[r0 + r][j] = a0[r]; O1[r0 + r][j] = a1[r]; }
}

template <int ADD>
__device__ __forceinline__ void mix_bn(
    const float (*T0)[HID], const float (*T1)[HID], const float (*A)[KJ],
    const float* __restrict__ bias, const float* __restrict__ gamma,
    const float* __restrict__ beta, float (*dst)[HID], int t) {
  const int d = t & 127;
  const int q = t >> 7;
  const float bsv = bias[d];
  const float gsv = gamma[d] * 0.99999500003749969f;  // rsqrt(1+1e-5)
  const float btv = beta[d];
  for (int i = q; i < KJ; i += 4) {
    float s = 0.f;
    #pragma unroll
    for (int jj = 0; jj < KJ; ++jj) s = fmaf(A[i][jj], T1[jj][d], s);
    s += A[i][i] * (T0[i][d] - T1[i][d]);   // replace diag term h1 -> h0
    const float v = fmaxf(fmaf(s + bsv, gsv, btv), 0.f);
    if (ADD) dst[i][d] += v; else dst[i][d] = v;
  }
}

__global__ __launch_bounds__(512) void k_gcn(
    const float* __restrict__ part,
    const float* __restrict__ Ei, const float* __restrict__ bi,
    const float* __restrict__ gi, const float* __restrict__ bti,
    const float* __restrict__ Wh, const float* __restrict__ bh,
    const float* __restrict__ Eh, const float* __restrict__ gh,
    const float* __restrict__ bth, const float* __restrict__ Wo,
    const float* __restrict__ bo, const float* __restrict__ Eo,
    float* __restrict__ out) {
  __shared__ float adjm[10][KJ][KJ];
  __shared__ float Hs[20][HID], Rs[20][HID], T0[20][HID], T1[20][HID];
  const int n = blockIdx.x, t = threadIdx.x;

  // 0) adjacency softmax for all 10 gconvs (Ei, Eh[0..7], Eo)
  if (t < 170) {
    const int m = t / KJ, i = t % KJ;
    const float* Es = (m == 0) ? Ei : ((m <= 8) ? Eh + (size_t)(m - 1) * KJ * KJ : Eo);
    const unsigned msk = c_mask[i];
    float mx = -1e30f;
    #pragma unroll
    for (int jj = 0; jj < KJ; ++jj)
      if (msk & (1u << jj)) mx = fmaxf(mx, Es[i * KJ + jj]);
    float ev[KJ];
    float sum = 0.f;
    #pragma unroll
    for (int jj = 0; jj < KJ; ++jj) {
      const float e = (msk & (1u << jj)) ? expf(Es[i * KJ + jj] - mx) : 0.f;
      ev[jj] = e; sum += e;
    }
    const float inv = 1.f / sum;
    #pragma unroll
    for (int jj = 0; jj < KJ; ++jj) adjm[m][i][jj] = ev[jj] * inv;
  }
  // zero pad-rows 17..19 (quarter 3 reads/writes them; S-pad must be 0)
  if (t < 384) { Hs[17 + (t >> 7)][t & 127] = 0.f; Rs[17 + (t >> 7)][t & 127] = 0.f; }

  // 1) sum split-K partials of input gconv h0/h1
  {
    const float* p0 = part + (size_t)(n * KJ) * 256;
    for (int idx = t; idx < KJ * 256; idx += 512) {
      const int k = idx >> 8, jj = idx & 255;
      float v = 0.f;
      #pragma unroll
      for (int z = 0; z < SPLITK; ++z)
        v += p0[(size_t)z * NROWS * 256 + k * 256 + jj];
      if (jj < HID) T0[k][jj] = v; else T1[k][jj - HID] = v;
    }
  }
  __syncthreads();

  // 2) input mixing + BN + ReLU -> Hs
  mix_bn<0>(T0, T1, adjm[0], bi, gi, bti, Hs, t);
  __syncthreads();

  // 3) 4 residual blocks x 2 gconvs
  for (int l = 0; l < 4; ++l) {
    const float* WA = Wh + (size_t)(2 * l) * 2 * HID * HID;
    const float* WB = WA + 2 * HID * HID;
    layer_compute(Hs, WA, T0, T1, t);
    __syncthreads();
    mix_bn<0>(T0, T1, adjm[1 + 2 * l], bh + (2 * l) * HID, gh + (2 * l) * HID,
              bth + (2 * l) * HID, Rs, t);
    __syncthreads();
    layer_compute(Rs, WB, T0, T1, t);
    __syncthreads();
    mix_bn<1>(T0, T1, adjm[2 + 2 * l], bh + (2 * l + 1) * HID, gh + (2 * l + 1) * HID,
              bth + (2 * l + 1) * HID, Hs, t);
    __syncthreads();
  }

  // 4) output gconv (no BN/ReLU): 128 -> 3
  if (t < 102) {
    const int p = t / 51, rem = t % 51, i = rem / 3, e = rem % 3;
    const float* Wp = Wo + p * HID * 3 + e;
    float s = 0.f;
    #pragma unroll 4
    for (int c = 0; c < HID; ++c) s = fmaf(Hs[i][c], Wp[c * 3], s);
    if (p == 0) T0[i][e] = s; else T1[i][e] = s;
  }
  __syncthreads();
  if (t < 51) {
    const int i = t / 3, e = t % 3;
    const float (*A)[KJ] = adjm[9];
    float s = bo[e];
    #pragma unroll
    for (int jj = 0; jj < KJ; ++jj) s = fmaf(A[i][jj], T1[jj][e], s);
    s += A[i][i] * (T0[i][e] - T1[i][e]);
    out[(n * KJ + i) * 3 + e] = s;
  }
}

// ---------------------------------------------------------------------------
extern "C" void kernel_launch(void* const* d_in, const int* in_sizes, int n_in,
                              void* d_out, int out_size, void* d_ws, size_t ws_size,
                              hipStream_t stream) {
  const float* x       = (const float*)d_in[0];
  const float* heatmap = (const float*)d_in[1];
  const float* bbox    = (const float*)d_in[2];
  const float* pos_w   = (const float*)d_in[3];
  const float* pos_b   = (const float*)d_in[4];
  const float* Wi      = (const float*)d_in[5];
  const float* bi      = (const float*)d_in[6];
  const float* Ei      = (const float*)d_in[7];
  const float* gi      = (const float*)d_in[8];
  const float* bti     = (const float*)d_in[9];
  const float* Wh      = (const float*)d_in[10];
  const float* bh      = (const float*)d_in[11];
  const float* Eh      = (const float*)d_in[12];
  const float* gh      = (const float*)d_in[13];
  const float* bth     = (const float*)d_in[14];
  const float* Wo      = (const float*)d_in[15];
  const float* bo      = (const float*)d_in[16];
  const float* Eo      = (const float*)d_in[17];
  float* out = (float*)d_out;

  // ws layout (floats): h[544*2112] | part[4*544*256] | locs[544] (as int)
  float* h_ws = (float*)d_ws;
  float* part = h_ws + (size_t)NROWS * CEMB;
  int*   locs = (int*)(part + (size_t)SPLITK * NROWS * 256);

  k_loc<<<NROWS, 256, 0, stream>>>(heatmap, bbox, pos_w, pos_b, h_ws, locs);
  k_feat<<<dim3(NROWS, 4), 256, 0, stream>>>(x, locs, h_ws);
  k_gemm_in<<<dim3(34, 4, SPLITK), 256, 0, stream>>>(h_ws, Wi, part);
  k_gcn<<<NB, 512, 0, stream>>>(part, Ei, bi, gi, bti, Wh, bh, Eh, gh, bth,
                                Wo, bo, Eo, out);
}